// Round 1
// baseline (758.269 us; speedup 1.0000x reference)
//
#include <hip/hip_runtime.h>
#include <hip/hip_bf16.h>

typedef __bf16 bf16_t;
typedef bf16_t bf16x8 __attribute__((ext_vector_type(8)));
typedef float f32x4 __attribute__((ext_vector_type(4)));

typedef __attribute__((address_space(3))) unsigned int lds_u32;
typedef __attribute__((address_space(1))) unsigned int glb_u32;

__device__ __forceinline__ float bflo(unsigned int p){ union{unsigned int u; float f;} c; c.u = p << 16; return c.f; }
__device__ __forceinline__ float bfhi(unsigned int p){ union{unsigned int u; float f;} c; c.u = p & 0xffff0000u; return c.f; }
__device__ __forceinline__ unsigned int f2bfu(float f){
  union{float f; unsigned int u;} c; c.f = f;
  return (c.u + 0x7fffu + ((c.u >> 16) & 1u)) >> 16;
}

// ---------------- cast x (f32 -> bf16 pairs) ----------------
__global__ void k_cast_x(const float2* __restrict__ x, unsigned int* __restrict__ xb, int npairs){
  int stride = gridDim.x * blockDim.x;
  for (int i = blockIdx.x * blockDim.x + threadIdx.x; i < npairs; i += stride){
    float2 v = x[i];
    xb[i] = f2bfu(v.x) | (f2bfu(v.y) << 16);
  }
}

// ---------------- cast + transpose weight 384x384: WT[n][k] = bf16(W[k][n]) ----------------
__global__ void k_castT_w(const float* __restrict__ W, unsigned short* __restrict__ WT){
  int idx = blockIdx.x * 256 + threadIdx.x;   // 0..147455
  int k = idx / 384, n = idx % 384;
  WT[n * 384 + k] = (unsigned short)f2bfu(W[idx]);
}

// ---------------- degree count ----------------
__global__ void k_deg(const int* __restrict__ dst, int* __restrict__ deg, int E){
  int stride = gridDim.x * blockDim.x;
  for (int e = blockIdx.x * blockDim.x + threadIdx.x; e < E; e += stride)
    atomicAdd(&deg[dst[e]], 1);
}

// ---------------- single-block prefix scan -> rowptr, cursor ----------------
__global__ void k_scan(const int* __restrict__ deg, int* __restrict__ rowptr, int* __restrict__ cursor, int n){
  __shared__ int wsum[16];
  __shared__ int carry;
  int t = threadIdx.x, l = t & 63, w = t >> 6;
  if (t == 0){ carry = 0; rowptr[0] = 0; }
  __syncthreads();
  for (int base = 0; base < n; base += 1024){
    int i = base + t;
    int v = (i < n) ? deg[i] : 0;
    int xv = v;
    #pragma unroll
    for (int s = 1; s < 64; s <<= 1){
      int y = __shfl_up(xv, s, 64);
      if (l >= s) xv += y;
    }
    if (l == 63) wsum[w] = xv;
    __syncthreads();
    int off = carry;
    for (int k2 = 0; k2 < w; ++k2) off += wsum[k2];
    if (i < n){
      rowptr[i + 1] = off + xv;
      cursor[i] = off + xv - v;
    }
    __syncthreads();
    if (t == 0){
      int tot = 0;
      for (int k2 = 0; k2 < 16; ++k2) tot += wsum[k2];
      carry += tot;
    }
    __syncthreads();
  }
}

// ---------------- CSR fill ----------------
__global__ void k_fill(const int* __restrict__ src, const int* __restrict__ dst, const float* __restrict__ ew,
                       int* __restrict__ cursor, int* __restrict__ csr_src, float* __restrict__ csr_w, int E){
  int stride = gridDim.x * blockDim.x;
  for (int e = blockIdx.x * blockDim.x + threadIdx.x; e < E; e += stride){
    int d = dst[e];
    int pos = atomicAdd(&cursor[d], 1);
    csr_src[pos] = src[e];
    csr_w[pos] = ew[e];
  }
}

// ---------------- mean aggregation: one wave per node, bf16 in -> bf16 out ----------------
__global__ void k_agg(const unsigned short* __restrict__ X, unsigned short* __restrict__ OUT,
                      const int* __restrict__ rowptr, const int* __restrict__ csr_src,
                      const float* __restrict__ csr_w, int n_nodes){
  int w = threadIdx.x >> 6, l = threadIdx.x & 63;
  int node = blockIdx.x * 4 + w;
  if (node >= n_nodes) return;
  int e0 = rowptr[node], e1 = rowptr[node + 1];
  float a0=0,a1=0,a2=0,a3=0,a4=0,a5=0;
  const unsigned int* X32 = (const unsigned int*)X;
  for (int e = e0; e < e1; ++e){
    int s = csr_src[e];
    float wt = csr_w[e];
    const unsigned int* xr = X32 + (long)s * 192;
    unsigned int p0 = xr[l], p1 = xr[l + 64], p2 = xr[l + 128];
    a0 += wt * bflo(p0); a1 += wt * bfhi(p0);
    a2 += wt * bflo(p1); a3 += wt * bfhi(p1);
    a4 += wt * bflo(p2); a5 += wt * bfhi(p2);
  }
  int degn = e1 - e0;
  float inv = 1.0f / (float)(degn > 1 ? degn : 1);
  unsigned int* O32 = (unsigned int*)OUT + (long)node * 192;
  O32[l]       = f2bfu(a0 * inv) | (f2bfu(a1 * inv) << 16);
  O32[l + 64]  = f2bfu(a2 * inv) | (f2bfu(a3 * inv) << 16);
  O32[l + 128] = f2bfu(a4 * inv) | (f2bfu(a5 * inv) << 16);
}

// ---------------- fused dual GEMM: C = relu(A1@B1 + bias + A2@B2) ----------------
// A row-major [NN,384] bf16; B = WT [384n][384k] bf16 (pre-transposed).
template<int OUT_BF16>
__global__ __launch_bounds__(256) void k_gemm(
    const unsigned short* __restrict__ A1, const unsigned short* __restrict__ B1,
    const unsigned short* __restrict__ A2, const unsigned short* __restrict__ B2,
    const float* __restrict__ bias, void* __restrict__ Cout, int NN)
{
  __shared__ __align__(16) unsigned short lsA[128 * 32];
  __shared__ __align__(16) unsigned short lsB[128 * 32];
  int t = threadIdx.x;
  int w = t >> 6, l = t & 63;
  int m0 = blockIdx.y * 128;
  int n0 = blockIdx.x * 128;
  int wrow = (w & 1) * 64, wcol = (w >> 1) * 64;

  f32x4 acc[4][4] = {};

  int ar = t >> 2, ac = t & 3;
  int ra0 = m0 + ar;       if (ra0 >= NN) ra0 = NN - 1;
  int ra1 = m0 + 64 + ar;  if (ra1 >= NN) ra1 = NN - 1;
  int rb0 = n0 + ar, rb1 = n0 + 64 + ar;

  for (int ph = 0; ph < 2; ++ph){
    const unsigned short* Ag = ph ? A2 : A1;
    const unsigned short* Bg = ph ? B2 : B1;
    for (int k0 = 0; k0 < 384; k0 += 32){
      int kc = k0 + ac * 8;
      __builtin_amdgcn_global_load_lds((glb_u32*)(Ag + (long)ra0 * 384 + kc),
                                       (lds_u32*)((char*)lsA + w * 1024), 16, 0, 0);
      __builtin_amdgcn_global_load_lds((glb_u32*)(Ag + (long)ra1 * 384 + kc),
                                       (lds_u32*)((char*)lsA + 4096 + w * 1024), 16, 0, 0);
      __builtin_amdgcn_global_load_lds((glb_u32*)(Bg + (long)rb0 * 384 + kc),
                                       (lds_u32*)((char*)lsB + w * 1024), 16, 0, 0);
      __builtin_amdgcn_global_load_lds((glb_u32*)(Bg + (long)rb1 * 384 + kc),
                                       (lds_u32*)((char*)lsB + 4096 + w * 1024), 16, 0, 0);
      __syncthreads();
      int koff = (l >> 4) * 8;
      int rA = wrow + (l & 15);
      int rB = wcol + (l & 15);
      bf16x8 af[4], bf[4];
      #pragma unroll
      for (int mi = 0; mi < 4; ++mi) af[mi] = *(const bf16x8*)&lsA[(rA + mi * 16) * 32 + koff];
      #pragma unroll
      for (int ni = 0; ni < 4; ++ni) bf[ni] = *(const bf16x8*)&lsB[(rB + ni * 16) * 32 + koff];
      #pragma unroll
      for (int mi = 0; mi < 4; ++mi)
        #pragma unroll
        for (int ni = 0; ni < 4; ++ni)
          acc[mi][ni] = __builtin_amdgcn_mfma_f32_16x16x32_bf16(af[mi], bf[ni], acc[mi][ni], 0, 0, 0);
      __syncthreads();
    }
  }

  int colb = l & 15, rowb = (l >> 4) * 4;
  #pragma unroll
  for (int mi = 0; mi < 4; ++mi){
    #pragma unroll
    for (int ni = 0; ni < 4; ++ni){
      f32x4 v = acc[mi][ni];
      int col = n0 + wcol + ni * 16 + colb;
      float bcol = bias[col];
      #pragma unroll
      for (int r = 0; r < 4; ++r){
        int row = m0 + wrow + mi * 16 + rowb + r;
        if (row < NN){
          float val = fmaxf(v[r] + bcol, 0.0f);
          if (OUT_BF16) ((unsigned short*)Cout)[(long)row * 384 + col] = (unsigned short)f2bfu(val);
          else          ((float*)Cout)[(long)row * 384 + col] = val;
        }
      }
    }
  }
}

// ---------------- final linear [384,2] + sigmoid: one wave per node ----------------
__global__ void k_out(const float* __restrict__ Y, const float* __restrict__ WL,
                      const float* __restrict__ bl, float* __restrict__ out, int n_nodes){
  int w = threadIdx.x >> 6, l = threadIdx.x & 63;
  int node = blockIdx.x * 4 + w;
  if (node >= n_nodes) return;
  const float* yr = Y + (long)node * 384;
  float s0 = 0.f, s1 = 0.f;
  #pragma unroll
  for (int j = 0; j < 6; ++j){
    int d = l + 64 * j;
    float v = yr[d];
    s0 += v * WL[2 * d];
    s1 += v * WL[2 * d + 1];
  }
  #pragma unroll
  for (int m = 32; m; m >>= 1){
    s0 += __shfl_xor(s0, m);
    s1 += __shfl_xor(s1, m);
  }
  if (l == 0){
    out[(long)node * 2]     = 1.f / (1.f + expf(-(s0 + bl[0])));
    out[(long)node * 2 + 1] = 1.f / (1.f + expf(-(s1 + bl[1])));
  }
}

extern "C" void kernel_launch(void* const* d_in, const int* in_sizes, int n_in,
                              void* d_out, int out_size, void* d_ws, size_t ws_size,
                              hipStream_t stream) {
  const float* x      = (const float*)d_in[0];
  const int*   ei     = (const int*)d_in[1];
  const float* ew     = (const float*)d_in[2];
  const float* Wrel1  = (const float*)d_in[3];
  const float* brel1  = (const float*)d_in[4];
  const float* Wroot1 = (const float*)d_in[5];
  const float* Wrel2  = (const float*)d_in[6];
  const float* brel2  = (const float*)d_in[7];
  const float* Wroot2 = (const float*)d_in[8];
  const float* Wlin   = (const float*)d_in[9];
  const float* blin   = (const float*)d_in[10];

  const int NN = in_sizes[0] / 384;
  const int E  = in_sizes[2];
  const int* src = ei;
  const int* dst = ei + E;

  char* p = (char*)d_ws;
  auto carve = [&](size_t bytes) -> void* {
    void* r = (void*)p;
    p += (bytes + 255) & ~(size_t)255;
    return r;
  };
  int*   deg     = (int*)carve((size_t)NN * 4);
  int*   rowptr  = (int*)carve((size_t)(NN + 1) * 4);
  int*   cursor  = (int*)carve((size_t)NN * 4);
  int*   csr_src = (int*)carve((size_t)E * 4);
  float* csr_w   = (float*)carve((size_t)E * 4);
  unsigned short* xb  = (unsigned short*)carve((size_t)NN * 384 * 2);
  unsigned short* m1b = (unsigned short*)carve((size_t)NN * 384 * 2);  // reused as m2b
  unsigned short* hb  = (unsigned short*)carve((size_t)NN * 384 * 2);
  unsigned short* WT1 = (unsigned short*)carve(384 * 384 * 2);
  unsigned short* WT2 = (unsigned short*)carve(384 * 384 * 2);
  unsigned short* WT3 = (unsigned short*)carve(384 * 384 * 2);
  unsigned short* WT4 = (unsigned short*)carve(384 * 384 * 2);

  float* out = (float*)d_out;
  float* Y   = out + (size_t)NN * 2;

  hipMemsetAsync(deg, 0, (size_t)NN * 4, stream);
  k_cast_x<<<2048, 256, 0, stream>>>((const float2*)x, (unsigned int*)xb, NN * 192);
  k_castT_w<<<576, 256, 0, stream>>>(Wrel1,  WT1);
  k_castT_w<<<576, 256, 0, stream>>>(Wroot1, WT2);
  k_castT_w<<<576, 256, 0, stream>>>(Wrel2,  WT3);
  k_castT_w<<<576, 256, 0, stream>>>(Wroot2, WT4);
  k_deg<<<1024, 256, 0, stream>>>(dst, deg, E);
  k_scan<<<1, 1024, 0, stream>>>(deg, rowptr, cursor, NN);
  k_fill<<<1024, 256, 0, stream>>>(src, dst, ew, cursor, csr_src, csr_w, E);

  int aggBlocks = (NN + 3) / 4;
  k_agg<<<aggBlocks, 256, 0, stream>>>(xb, m1b, rowptr, csr_src, csr_w, NN);

  dim3 ggrid(3, (NN + 127) / 128);
  k_gemm<1><<<ggrid, 256, 0, stream>>>(m1b, WT1, xb, WT2, brel1, (void*)hb, NN);

  k_agg<<<aggBlocks, 256, 0, stream>>>(hb, m1b, rowptr, csr_src, csr_w, NN);

  k_gemm<0><<<ggrid, 256, 0, stream>>>(m1b, WT3, hb, WT4, brel2, (void*)Y, NN);

  k_out<<<aggBlocks, 256, 0, stream>>>(Y, Wlin, blin, out, NN);
}

// Round 2
// 590.376 us; speedup vs baseline: 1.2844x; 1.2844x over previous
//
#include <hip/hip_runtime.h>
#include <hip/hip_bf16.h>

typedef __bf16 bf16_t;
typedef bf16_t bf16x8 __attribute__((ext_vector_type(8)));
typedef float f32x4 __attribute__((ext_vector_type(4)));

typedef __attribute__((address_space(3))) unsigned int lds_u32;
typedef __attribute__((address_space(1))) unsigned int glb_u32;

__device__ __forceinline__ float bflo(unsigned int p){ union{unsigned int u; float f;} c; c.u = p << 16; return c.f; }
__device__ __forceinline__ float bfhi(unsigned int p){ union{unsigned int u; float f;} c; c.u = p & 0xffff0000u; return c.f; }
__device__ __forceinline__ unsigned int f2bfu(float f){
  union{float f; unsigned int u;} c; c.f = f;
  return (c.u + 0x7fffu + ((c.u >> 16) & 1u)) >> 16;
}

// ---------------- cast x (f32 -> bf16 pairs), float4 loads ----------------
__global__ void k_cast_x(const float4* __restrict__ x, uint2* __restrict__ xb, int nq){
  int stride = gridDim.x * blockDim.x;
  for (int i = blockIdx.x * blockDim.x + threadIdx.x; i < nq; i += stride){
    float4 v = x[i];
    uint2 o;
    o.x = f2bfu(v.x) | (f2bfu(v.y) << 16);
    o.y = f2bfu(v.z) | (f2bfu(v.w) << 16);
    xb[i] = o;
  }
}

// ---------------- cast + transpose 4 weights in one launch ----------------
__global__ void k_castT_w4(const float* __restrict__ W0, const float* __restrict__ W1,
                           const float* __restrict__ W2, const float* __restrict__ W3,
                           unsigned short* __restrict__ T0, unsigned short* __restrict__ T1,
                           unsigned short* __restrict__ T2, unsigned short* __restrict__ T3){
  const float* W; unsigned short* T;
  switch (blockIdx.y){
    case 0: W = W0; T = T0; break;
    case 1: W = W1; T = T1; break;
    case 2: W = W2; T = T2; break;
    default: W = W3; T = T3; break;
  }
  int idx = blockIdx.x * 256 + threadIdx.x;   // 0..147455
  int k = idx / 384, n = idx - k * 384;
  T[n * 384 + k] = (unsigned short)f2bfu(W[idx]);
}

// ---------------- degree count ----------------
__global__ void k_deg(const int* __restrict__ dst, int* __restrict__ deg, int E){
  int stride = gridDim.x * blockDim.x;
  for (int e = blockIdx.x * blockDim.x + threadIdx.x; e < E; e += stride)
    atomicAdd(&deg[dst[e]], 1);
}

// ---------------- parallel scan, 3 kernels ----------------
__global__ void k_scan1(const int* __restrict__ deg, int* __restrict__ incl,
                        int* __restrict__ bsum, int n){
  __shared__ int wsum[16];
  int t = threadIdx.x, l = t & 63, w = t >> 6;
  int i = blockIdx.x * 1024 + t;
  int v = (i < n) ? deg[i] : 0;
  int xv = v;
  #pragma unroll
  for (int s = 1; s < 64; s <<= 1){
    int y = __shfl_up(xv, s, 64);
    if (l >= s) xv += y;
  }
  if (l == 63) wsum[w] = xv;
  __syncthreads();
  int off = 0;
  for (int k2 = 0; k2 < w; ++k2) off += wsum[k2];
  if (i < n) incl[i] = off + xv;
  if (t == 0){
    int tot = 0;
    for (int k2 = 0; k2 < 16; ++k2) tot += wsum[k2];
    bsum[blockIdx.x] = tot;
  }
}

__global__ void k_scan2(int* __restrict__ bsum, int nb){   // 128 threads, nb <= 128
  __shared__ int wtot;
  int t = threadIdx.x, l = t & 63, w = t >> 6;
  int v = (t < nb) ? bsum[t] : 0;
  int xv = v;
  #pragma unroll
  for (int s = 1; s < 64; s <<= 1){
    int y = __shfl_up(xv, s, 64);
    if (l >= s) xv += y;
  }
  if (t == 63) wtot = xv;
  __syncthreads();
  int off = (w == 1) ? wtot : 0;
  if (t < nb) bsum[t] = off + xv - v;    // exclusive
}

__global__ void k_scan3(const int* __restrict__ incl, const int* __restrict__ bsum,
                        const int* __restrict__ deg, int* __restrict__ rowptr,
                        int* __restrict__ cursor, int n){
  int i = blockIdx.x * 256 + threadIdx.x;
  if (i < n){
    int r = incl[i] + bsum[i >> 10];
    rowptr[i + 1] = r;
    cursor[i] = r - deg[i];
  }
  if (i == 0) rowptr[0] = 0;
}

// ---------------- CSR fill: packed {src, weight_bits} ----------------
__global__ void k_fill(const int* __restrict__ src, const int* __restrict__ dst, const float* __restrict__ ew,
                       int* __restrict__ cursor, int2* __restrict__ csr, int E){
  int stride = gridDim.x * blockDim.x;
  for (int e = blockIdx.x * blockDim.x + threadIdx.x; e < E; e += stride){
    int d = dst[e];
    int pos = atomicAdd(&cursor[d], 1);
    int2 c; c.x = src[e]; c.y = __float_as_int(ew[e]);
    csr[pos] = c;
  }
}

// ---------------- mean aggregation: one wave per node, 2x unrolled ----------------
__global__ void k_agg(const unsigned short* __restrict__ X, unsigned short* __restrict__ OUT,
                      const int* __restrict__ rowptr, const int2* __restrict__ csr, int n_nodes){
  int w = threadIdx.x >> 6, l = threadIdx.x & 63;
  int node = blockIdx.x * 4 + w;
  if (node >= n_nodes) return;
  int e0 = rowptr[node], e1 = rowptr[node + 1];
  float a0=0,a1=0,a2=0,a3=0,a4=0,a5=0;
  const unsigned int* X32 = (const unsigned int*)X;
  int e = e0;
  for (; e + 2 <= e1; e += 2){
    int2 c0 = csr[e], c1 = csr[e + 1];
    const unsigned int* x0 = X32 + (long)c0.x * 192;
    const unsigned int* x1 = X32 + (long)c1.x * 192;
    unsigned int p0 = x0[l], p1 = x0[l + 64], p2 = x0[l + 128];
    unsigned int q0 = x1[l], q1 = x1[l + 64], q2 = x1[l + 128];
    float w0 = __int_as_float(c0.y), w1 = __int_as_float(c1.y);
    a0 += w0 * bflo(p0); a1 += w0 * bfhi(p0);
    a2 += w0 * bflo(p1); a3 += w0 * bfhi(p1);
    a4 += w0 * bflo(p2); a5 += w0 * bfhi(p2);
    a0 += w1 * bflo(q0); a1 += w1 * bfhi(q0);
    a2 += w1 * bflo(q1); a3 += w1 * bfhi(q1);
    a4 += w1 * bflo(q2); a5 += w1 * bfhi(q2);
  }
  if (e < e1){
    int2 c0 = csr[e];
    const unsigned int* x0 = X32 + (long)c0.x * 192;
    unsigned int p0 = x0[l], p1 = x0[l + 64], p2 = x0[l + 128];
    float w0 = __int_as_float(c0.y);
    a0 += w0 * bflo(p0); a1 += w0 * bfhi(p0);
    a2 += w0 * bflo(p1); a3 += w0 * bfhi(p1);
    a4 += w0 * bflo(p2); a5 += w0 * bfhi(p2);
  }
  int degn = e1 - e0;
  float inv = 1.0f / (float)(degn > 1 ? degn : 1);
  unsigned int* O32 = (unsigned int*)OUT + (long)node * 192;
  O32[l]       = f2bfu(a0 * inv) | (f2bfu(a1 * inv) << 16);
  O32[l + 64]  = f2bfu(a2 * inv) | (f2bfu(a3 * inv) << 16);
  O32[l + 128] = f2bfu(a4 * inv) | (f2bfu(a5 * inv) << 16);
}

// ---------------- fused dual GEMM, double-buffered + swizzled ----------------
// C = relu(A1@B1^T + bias + A2@B2^T), A row-major [NN,384] bf16, B = WT [384n][384k] bf16.
template<int OUT_BF16>
__global__ __launch_bounds__(256) void k_gemm(
    const unsigned short* __restrict__ A1, const unsigned short* __restrict__ B1,
    const unsigned short* __restrict__ A2, const unsigned short* __restrict__ B2,
    const float* __restrict__ bias, void* __restrict__ Cout, int NN, int q, int r)
{
  __shared__ __align__(16) unsigned short lsA[2 * 128 * 32];
  __shared__ __align__(16) unsigned short lsB[2 * 128 * 32];
  int t = threadIdx.x;
  int w = t >> 6, l = t & 63;

  // bijective XCD swizzle (m204): 3 N-tiles of a row panel land contiguously on one XCD
  int lin = blockIdx.y * 3 + blockIdx.x;
  int xcd = lin & 7, idx = lin >> 3;
  int nl = idx + ((xcd < r) ? xcd * (q + 1) : r * (q + 1) + (xcd - r) * q);
  int mt = nl / 3, nt = nl - mt * 3;
  int m0 = mt * 128;
  int n0 = nt * 128;
  int wrow = (w & 1) * 64, wcol = (w >> 1) * 64;

  f32x4 acc[4][4] = {};

  int ar = t >> 2, ac = t & 3;
  int sw = (ar >> 1) & 3;                    // T2 pre-swizzle of global chunk
  int acs = (ac ^ sw) * 8;
  int ra0 = m0 + ar;       if (ra0 >= NN) ra0 = NN - 1;
  int ra1 = m0 + 64 + ar;  if (ra1 >= NN) ra1 = NN - 1;
  int rb0 = n0 + ar, rb1 = n0 + 64 + ar;

  char* lsAb = (char*)lsA;
  char* lsBb = (char*)lsB;

#define STAGE(buf, kk) do { \
    const unsigned short* Ag = ((kk) < 12) ? A1 : A2; \
    const unsigned short* Bg = ((kk) < 12) ? B1 : B2; \
    int kc = ((((kk) < 12) ? (kk) : (kk) - 12) << 5) + acs; \
    __builtin_amdgcn_global_load_lds((glb_u32*)(Ag + (long)ra0 * 384 + kc), (lds_u32*)(lsAb + (buf) * 8192 + w * 1024), 16, 0, 0); \
    __builtin_amdgcn_global_load_lds((glb_u32*)(Ag + (long)ra1 * 384 + kc), (lds_u32*)(lsAb + (buf) * 8192 + 4096 + w * 1024), 16, 0, 0); \
    __builtin_amdgcn_global_load_lds((glb_u32*)(Bg + (long)rb0 * 384 + kc), (lds_u32*)(lsBb + (buf) * 8192 + w * 1024), 16, 0, 0); \
    __builtin_amdgcn_global_load_lds((glb_u32*)(Bg + (long)rb1 * 384 + kc), (lds_u32*)(lsBb + (buf) * 8192 + 4096 + w * 1024), 16, 0, 0); \
  } while (0)

  STAGE(0, 0);
  __syncthreads();

  int rA = wrow + (l & 15);
  int rB = wcol + (l & 15);
  int swA = (rA >> 1) & 3, swB = (rB >> 1) & 3;
  int kchunk = l >> 4;
  int offA = ((kchunk ^ swA) * 8);
  int offB = ((kchunk ^ swB) * 8);

  for (int kk = 0; kk < 24; ++kk){
    int cur = kk & 1;
    if (kk < 23) STAGE(cur ^ 1, kk + 1);     // prefetch flies under the MFMAs
    const unsigned short* bA = lsA + cur * 4096;
    const unsigned short* bB = lsB + cur * 4096;
    bf16x8 af[4], bfr[4];
    #pragma unroll
    for (int mi = 0; mi < 4; ++mi) af[mi]  = *(const bf16x8*)&bA[(rA + mi * 16) * 32 + offA];
    #pragma unroll
    for (int ni = 0; ni < 4; ++ni) bfr[ni] = *(const bf16x8*)&bB[(rB + ni * 16) * 32 + offB];
    #pragma unroll
    for (int mi = 0; mi < 4; ++mi)
      #pragma unroll
      for (int ni = 0; ni < 4; ++ni)
        acc[mi][ni] = __builtin_amdgcn_mfma_f32_16x16x32_bf16(af[mi], bfr[ni], acc[mi][ni], 0, 0, 0);
    __syncthreads();                          // implicit vmcnt(0): prefetch had full MFMA window
  }
#undef STAGE

  int colb = l & 15, rowb = (l >> 4) * 4;
  #pragma unroll
  for (int mi = 0; mi < 4; ++mi){
    #pragma unroll
    for (int ni = 0; ni < 4; ++ni){
      f32x4 v = acc[mi][ni];
      int col = n0 + wcol + ni * 16 + colb;
      float bcol = bias[col];
      #pragma unroll
      for (int rr = 0; rr < 4; ++rr){
        int row = m0 + wrow + mi * 16 + rowb + rr;
        if (row < NN){
          float val = fmaxf(v[rr] + bcol, 0.0f);
          if (OUT_BF16) ((unsigned short*)Cout)[(long)row * 384 + col] = (unsigned short)f2bfu(val);
          else          ((float*)Cout)[(long)row * 384 + col] = val;
        }
      }
    }
  }
}

// ---------------- final linear [384,2] + sigmoid ----------------
__global__ void k_out(const float* __restrict__ Y, const float* __restrict__ WL,
                      const float* __restrict__ bl, float* __restrict__ out, int n_nodes){
  int w = threadIdx.x >> 6, l = threadIdx.x & 63;
  int node = blockIdx.x * 4 + w;
  if (node >= n_nodes) return;
  const float* yr = Y + (long)node * 384;
  float s0 = 0.f, s1 = 0.f;
  #pragma unroll
  for (int j = 0; j < 6; ++j){
    int d = l + 64 * j;
    float v = yr[d];
    s0 += v * WL[2 * d];
    s1 += v * WL[2 * d + 1];
  }
  #pragma unroll
  for (int m = 32; m; m >>= 1){
    s0 += __shfl_xor(s0, m);
    s1 += __shfl_xor(s1, m);
  }
  if (l == 0){
    out[(long)node * 2]     = 1.f / (1.f + expf(-(s0 + bl[0])));
    out[(long)node * 2 + 1] = 1.f / (1.f + expf(-(s1 + bl[1])));
  }
}

extern "C" void kernel_launch(void* const* d_in, const int* in_sizes, int n_in,
                              void* d_out, int out_size, void* d_ws, size_t ws_size,
                              hipStream_t stream) {
  const float* x      = (const float*)d_in[0];
  const int*   ei     = (const int*)d_in[1];
  const float* ew     = (const float*)d_in[2];
  const float* Wrel1  = (const float*)d_in[3];
  const float* brel1  = (const float*)d_in[4];
  const float* Wroot1 = (const float*)d_in[5];
  const float* Wrel2  = (const float*)d_in[6];
  const float* brel2  = (const float*)d_in[7];
  const float* Wroot2 = (const float*)d_in[8];
  const float* Wlin   = (const float*)d_in[9];
  const float* blin   = (const float*)d_in[10];

  const int NN = in_sizes[0] / 384;
  const int E  = in_sizes[2];
  const int* src = ei;
  const int* dst = ei + E;

  char* p = (char*)d_ws;
  auto carve = [&](size_t bytes) -> void* {
    void* r = (void*)p;
    p += (bytes + 255) & ~(size_t)255;
    return r;
  };
  int*   deg     = (int*)carve((size_t)NN * 4);
  int*   rowptr  = (int*)carve((size_t)(NN + 1) * 4);
  int*   cursor  = (int*)carve((size_t)NN * 4);
  int*   incl    = (int*)carve((size_t)NN * 4);
  int*   bsum    = (int*)carve(1024);
  int2*  csr     = (int2*)carve((size_t)E * 8);
  unsigned short* xb  = (unsigned short*)carve((size_t)NN * 384 * 2);
  unsigned short* m1b = (unsigned short*)carve((size_t)NN * 384 * 2);
  unsigned short* hb  = (unsigned short*)carve((size_t)NN * 384 * 2);
  unsigned short* WT1 = (unsigned short*)carve(384 * 384 * 2);
  unsigned short* WT2 = (unsigned short*)carve(384 * 384 * 2);
  unsigned short* WT3 = (unsigned short*)carve(384 * 384 * 2);
  unsigned short* WT4 = (unsigned short*)carve(384 * 384 * 2);

  float* out = (float*)d_out;
  float* Y   = out + (size_t)NN * 2;

  int nScanB = (NN + 1023) / 1024;

  hipMemsetAsync(deg, 0, (size_t)NN * 4, stream);
  k_cast_x<<<2048, 256, 0, stream>>>((const float4*)x, (uint2*)xb, NN * 96);
  dim3 wg(576, 4);
  k_castT_w4<<<wg, 256, 0, stream>>>(Wrel1, Wroot1, Wrel2, Wroot2, WT1, WT2, WT3, WT4);
  k_deg<<<1024, 256, 0, stream>>>(dst, deg, E);
  k_scan1<<<nScanB, 1024, 0, stream>>>(deg, incl, bsum, NN);
  k_scan2<<<1, 128, 0, stream>>>(bsum, nScanB);
  k_scan3<<<(NN + 255) / 256, 256, 0, stream>>>(incl, bsum, deg, rowptr, cursor, NN);
  k_fill<<<1024, 256, 0, stream>>>(src, dst, ew, cursor, csr, E);

  int aggBlocks = (NN + 3) / 4;
  k_agg<<<aggBlocks, 256, 0, stream>>>(xb, m1b, rowptr, csr, NN);

  int gy = (NN + 127) / 128;
  int nwg = 3 * gy, q = nwg >> 3, r = nwg & 7;
  dim3 ggrid(3, gy);
  k_gemm<1><<<ggrid, 256, 0, stream>>>(m1b, WT1, xb, WT2, brel1, (void*)hb, NN, q, r);

  k_agg<<<aggBlocks, 256, 0, stream>>>(hb, m1b, rowptr, csr, NN);

  k_gemm<0><<<ggrid, 256, 0, stream>>>(m1b, WT3, hb, WT4, brel2, (void*)Y, NN, q, r);

  k_out<<<aggBlocks, 256, 0, stream>>>(Y, Wlin, blin, out, NN);
}